// Round 6
// baseline (133.270 us; speedup 1.0000x reference)
//
#include <hip/hip_runtime.h>
#include <hip/hip_bf16.h>
#include <stdint.h>

// ---------------- problem constants ----------------
#define BATCH 16
#define CDIM  1024
#define FWID  32
#define HW    1024
#define NA    1024
#define NTOT  (BATCH*NA)    // 16384
#define NCHUNK 16           // 8 m-blocks * 2 waves in N
#define MARGIN 0.6f

typedef __bf16 bf16x8 __attribute__((ext_vector_type(8)));
typedef float  f32x4  __attribute__((ext_vector_type(4)));
typedef unsigned short us4 __attribute__((ext_vector_type(4)));
typedef unsigned short us8 __attribute__((ext_vector_type(8)));
typedef float  f4     __attribute__((ext_vector_type(4)));

template<int OFF>
__device__ __forceinline__ us4 tr_read(uint32_t addr){
  us4 r;
  asm volatile("ds_read_b64_tr_b16 %0, %1 offset:%2" : "=v"(r) : "v"(addr), "n"(OFF));
  return r;
}

__device__ __forceinline__ void gload16(const unsigned short* g, unsigned short* l){
  __builtin_amdgcn_global_load_lds((const __attribute__((address_space(1))) void*)g,
                                   (__attribute__((address_space(3))) void*)l, 16, 0, 0);
}

union FragU  { us4 h[2]; bf16x8 v; };
union FragU8 { us8 u;    bf16x8 v; };

__device__ __forceinline__ void ins3(float& a, float& b, float& c, float v){
  if (v < c){
    c = v;
    if (c < b){ float t=b; b=c; c=t;
      if (b < a){ t=a; a=b; b=t; }
    }
  }
}

#define MFMA __builtin_amdgcn_mfma_f32_16x16x32_bf16

// ---------------------------------------------------------------------------
// Pass 1: fp32 [c][hw] -> bf16 TRANSPOSED [hw][c]  + per-hw norm partials.
// grid: e(2) x b(16) x hwT(16) x cT(8) = 4096 blocks, 256 threads.
// Thread: hw_l = t>>2 (64 rows/block), cj = t&3; covers 32 c's (4 x us8).
// Reads lane-coalesced over hw (4B x 16 lanes = 64B); writes 64B-contiguous.
// ---------------------------------------------------------------------------
__global__ __launch_bounds__(256)
void convert_transpose(const float* __restrict__ S, const float* __restrict__ R,
                       unsigned short* __restrict__ tS, unsigned short* __restrict__ tR,
                       float* __restrict__ pnorm){
  const int blk = blockIdx.x;
  const int e   = blk >> 11;
  const int b   = (blk >> 7) & 15;
  const int hwT = (blk >> 3) & 15;
  const int cT  = blk & 7;
  const float* src = (e ? R : S) + (size_t)b*CDIM*HW;
  unsigned short* dst = (e ? tR : tS) + (size_t)b*HW*CDIM;

  const int t    = threadIdx.x;
  const int hw_l = t >> 2;
  const int cj   = t & 3;
  const int hw   = hwT*64 + hw_l;
  const int c0   = cT*128;

  float sq = 0.f;
  #pragma unroll
  for (int s = 0; s < 4; ++s){
    us8 pk;
    const int cb = c0 + s*32 + cj*8;
    #pragma unroll
    for (int i = 0; i < 8; ++i){
      const float v = src[(size_t)(cb + i)*HW + hw];
      __hip_bfloat16 h = __float2bfloat16(v);
      pk[i] = __builtin_bit_cast(unsigned short, h);
      const float g = __bfloat162float(h);
      sq = fmaf(g, g, sq);
    }
    *(us8*)&dst[(size_t)hw*CDIM + cb] = pk;
  }
  // reduce over cj (4-lane groups: t, t^1, t^2 share hw)
  sq += __shfl_xor(sq, 1);
  sq += __shfl_xor(sq, 2);
  if (cj == 0)
    pnorm[((size_t)(e*16 + b)*8 + cT)*HW + hw] = sq;
}

// grid: 32 blocks [e*16+b], 256 threads; snorm = sqrt(sum of 8 partials)
__global__ __launch_bounds__(256)
void norm_reduce(const float* __restrict__ pnorm, float* __restrict__ snorm){
  const int eb = blockIdx.x;
  const int t  = threadIdx.x;
  #pragma unroll
  for (int r = 0; r < 4; ++r){
    const int hw = r*256 + t;
    float a = 0.f;
    #pragma unroll
    for (int ct = 0; ct < 8; ++ct)
      a += pnorm[((size_t)eb*8 + ct)*HW + hw];
    snorm[(size_t)eb*HW + hw] = sqrtf(a);
  }
}

// ---------------------------------------------------------------------------
// Pass 2 (v3): m97-style NT GEMM on transposed bf16. 128x128 tile, BK=32,
// 4 waves, 2 LDS buffers, counted vmcnt(4), compiler-scheduled ds_read_b128
// fragment loads (k-contiguous), 4-chunk XOR swizzle (both-sides, rule 21).
// Gather of anchor rows is free (per-row global_load_lds sources).
// ---------------------------------------------------------------------------
__global__ __launch_bounds__(256)
void fused_gemm_top3_v3(const unsigned short* __restrict__ tS,
                        const unsigned short* __restrict__ tR,
                        const float* __restrict__ snorm,
                        const int*   __restrict__ anchor,
                        const int*   __restrict__ posidx,
                        float* __restrict__ wtop,   // [NTOT][NCHUNK][3]
                        float* __restrict__ wpos)   // [NTOT]
{
  // A: us [0,8192) (2 bufs x 4096 = [128 rows][32 c]); B: us [8192,16384)
  __shared__ unsigned short stage[16384];   // 32 KB
  __shared__ int   p_lds[128], q_lds[128];
  __shared__ float nAs[128], nBs[128];

  const int t = threadIdx.x;
  const uint32_t bid = blockIdx.x;
  const uint32_t L = (bid & 7u)*128u + (bid >> 3);   // XCD swizzle (bijective)
  const int b  = L >> 6;
  const int ni = (L >> 3) & 7;
  const int mi = L & 7;

  const unsigned short* SbT = tS + (size_t)b*HW*CDIM;
  const unsigned short* RbT = tR + (size_t)b*HW*CDIM;

  if (t < 128){
    const int n_g = ni*128 + t;
    const int* ap = anchor + (size_t)(b*NA + n_g)*3;
    const int* pp = posidx + (size_t)(b*NA + n_g)*3;
    p_lds[t] = ap[2]*FWID + ap[1];
    q_lds[t] = pp[2]*FWID + pp[1];
  }
  __syncthreads();

  const int mbase = mi*128;
  const int l  = t & 63;
  const int w  = t >> 6;
  const int wr = w >> 1, wc = w & 1;

  // ---- staging map: inst i covers rows (w*2+i)*16 + (l>>2), chunk pos l&3.
  // stored chunk pos p holds logical k-chunk kg = p ^ (row&3)  (XOR swizzle).
  const int rA0 = (w*2+0)*16 + (l>>2);
  const int rA1 = (w*2+1)*16 + (l>>2);
  const int kgl = (l&3) ^ ((l>>2)&3);
  const unsigned short* gA0 = SbT + (size_t)p_lds[rA0]*CDIM + kgl*8;
  const unsigned short* gA1 = SbT + (size_t)p_lds[rA1]*CDIM + kgl*8;
  const unsigned short* gB0 = RbT + (size_t)(mbase + rA0)*CDIM + kgl*8;
  const unsigned short* gB1 = RbT + (size_t)(mbase + rA1)*CDIM + kgl*8;
  unsigned short* lA0 = &stage[(w*2+0)*512];
  unsigned short* lA1 = &stage[(w*2+1)*512];
  unsigned short* lB0 = &stage[8192 + (w*2+0)*512];
  unsigned short* lB1 = &stage[8192 + (w*2+1)*512];

  // ---- frag read offsets (us units): row m at m*32, k-chunk (l>>4) swizzled
  const int sw   = ((l>>4) ^ (l&3))*8;
  const int aoff = (wr*64 + (l&15))*32 + sw;
  const int boff = 8192 + (wc*64 + (l&15))*32 + sw;

  f32x4 acc[4][4];
  #pragma unroll
  for (int i=0;i<4;i++){
    #pragma unroll
    for (int j=0;j<4;j++){ f32x4 z = {0.f,0.f,0.f,0.f}; acc[i][j] = z; }
  }

  auto stage_fn = [&](int buf, int kt){
    const size_t ko = (size_t)kt*32;
    gload16(gA0 + ko, lA0 + buf*4096);
    gload16(gA1 + ko, lA1 + buf*4096);
    gload16(gB0 + ko, lB0 + buf*4096);
    gload16(gB1 + ko, lB1 + buf*4096);
  };

  auto compute = [&](int buf){
    const int ab = buf*4096 + aoff;
    const int bb = buf*4096 + boff;
    FragU8 A0,A1,A2,A3,B0,B1,B2,B3;
    A0.u = *(const us8*)&stage[ab];
    A1.u = *(const us8*)&stage[ab +  512];
    A2.u = *(const us8*)&stage[ab + 1024];
    A3.u = *(const us8*)&stage[ab + 1536];
    B0.u = *(const us8*)&stage[bb];
    B1.u = *(const us8*)&stage[bb +  512];
    B2.u = *(const us8*)&stage[bb + 1024];
    B3.u = *(const us8*)&stage[bb + 1536];
    acc[0][0]=MFMA(A0.v,B0.v,acc[0][0],0,0,0);
    acc[0][1]=MFMA(A0.v,B1.v,acc[0][1],0,0,0);
    acc[0][2]=MFMA(A0.v,B2.v,acc[0][2],0,0,0);
    acc[0][3]=MFMA(A0.v,B3.v,acc[0][3],0,0,0);
    acc[1][0]=MFMA(A1.v,B0.v,acc[1][0],0,0,0);
    acc[1][1]=MFMA(A1.v,B1.v,acc[1][1],0,0,0);
    acc[1][2]=MFMA(A1.v,B2.v,acc[1][2],0,0,0);
    acc[1][3]=MFMA(A1.v,B3.v,acc[1][3],0,0,0);
    acc[2][0]=MFMA(A2.v,B0.v,acc[2][0],0,0,0);
    acc[2][1]=MFMA(A2.v,B1.v,acc[2][1],0,0,0);
    acc[2][2]=MFMA(A2.v,B2.v,acc[2][2],0,0,0);
    acc[2][3]=MFMA(A2.v,B3.v,acc[2][3],0,0,0);
    acc[3][0]=MFMA(A3.v,B0.v,acc[3][0],0,0,0);
    acc[3][1]=MFMA(A3.v,B1.v,acc[3][1],0,0,0);
    acc[3][2]=MFMA(A3.v,B2.v,acc[3][2],0,0,0);
    acc[3][3]=MFMA(A3.v,B3.v,acc[3][3],0,0,0);
  };

  // ---- main K loop: 32 tiles of BK=32, 2-buf, counted vmcnt (round-4 sync) ----
  stage_fn(0, 0);
  int buf = 0;
  for (int kt = 0; kt < 32; ++kt){
    if (kt < 31){
      stage_fn(buf^1, kt+1);
      asm volatile("s_waitcnt vmcnt(4)" ::: "memory");
    } else {
      asm volatile("s_waitcnt vmcnt(0)" ::: "memory");
    }
    asm volatile("s_barrier" ::: "memory");
    compute(buf);
    asm volatile("s_waitcnt lgkmcnt(0)" ::: "memory");
    asm volatile("s_barrier" ::: "memory");
    buf ^= 1;
  }

  // ---- norms from precomputed snorm ----
  if (t < 128) nAs[t] = snorm[(size_t)b*HW + p_lds[t]];
  else         nBs[t-128] = snorm[(size_t)(BATCH + b)*HW + mbase + (t-128)];
  __syncthreads();

  // ---- epilogue: normalize, positive capture, per-row top3-min ----
  float rncol[4];
  #pragma unroll
  for (int nf=0;nf<4;nf++) rncol[nf] = nBs[wc*64 + nf*16 + (l&15)];

  #pragma unroll
  for (int mf=0; mf<4; ++mf){
    #pragma unroll
    for (int r=0; r<4; ++r){
      const int row_l = wr*64 + mf*16 + (l>>4)*4 + r;   // D: col=lane&15, row=(lane>>4)*4+reg
      const int n_g   = ni*128 + row_l;
      const float an  = nAs[row_l];
      const float v0 = acc[mf][0][r] / fmaxf(an*rncol[0], 1e-8f);
      const float v1 = acc[mf][1][r] / fmaxf(an*rncol[1], 1e-8f);
      const float v2 = acc[mf][2][r] / fmaxf(an*rncol[2], 1e-8f);
      const float v3 = acc[mf][3][r] / fmaxf(an*rncol[3], 1e-8f);

      const int q  = q_lds[row_l];
      const int ql = q - (mbase + wc*64);
      if (ql >= 0 && ql < 64 && (ql & 15) == (l & 15)){
        const int sel = ql >> 4;
        const float pv = sel==0 ? v0 : sel==1 ? v1 : sel==2 ? v2 : v3;
        wpos[b*NA + n_g] = pv;
      }

      float x=1e30f, y=1e30f, z=1e30f;
      ins3(x,y,z,v0); ins3(x,y,z,v1); ins3(x,y,z,v2); ins3(x,y,z,v3);
      #pragma unroll
      for (int m=1; m<16; m<<=1){
        const float ox = __shfl_xor(x, m);
        const float oy = __shfl_xor(y, m);
        const float oz = __shfl_xor(z, m);
        ins3(x,y,z,ox); ins3(x,y,z,oy); ins3(x,y,z,oz);
      }
      if ((l & 15) == 0){
        float* dst = wtop + ((size_t)(b*NA + n_g)*NCHUNK + (mi*2 + wc))*3;
        dst[0]=x; dst[1]=y; dst[2]=z;
      }
    }
  }
}

// ---------------------------------------------------------------------------
// v1 (verified) fused kernel — fallback when workspace is too small.
// ---------------------------------------------------------------------------
__global__ __launch_bounds__(256)
void fused_gemm_top3_v1(const float* __restrict__ sketch,
                        const float* __restrict__ refk,
                        const int*   __restrict__ anchor,
                        const int*   __restrict__ posidx,
                        float* __restrict__ wtop,
                        float* __restrict__ wpos)
{
  __shared__ union {
    unsigned short stage[16384];
    struct { float nA[16][128]; float nB[16][128]; } nrm;
  } sh;
  __shared__ int   p_lds[128];
  __shared__ float nA2[128], nB2[128];

  const int t = threadIdx.x;
  const uint32_t bid = blockIdx.x;
  const uint32_t L = (bid & 7u)*128u + (bid >> 3);
  const int b  = L >> 6;
  const int ni = (L >> 3) & 7;
  const int mi = L & 7;

  const float* Sb = sketch + (size_t)b*CDIM*HW;
  const float* Rb = refk   + (size_t)b*CDIM*HW;

  if (t < 128){
    const int n_g = ni*128 + t;
    const int* ap = anchor + (size_t)(b*NA + n_g)*3;
    p_lds[t] = ap[2]*FWID + ap[1];
  }
  __syncthreads();
  const int p0 = p_lds[0];
  int okf = 1;
  if (t < 128) okf = (p_lds[t] == p0 + t);
  const int contig = __syncthreads_and(okf);

  const int colg = (t & 15)*8;
  const int rowg = t >> 4;
  const int mbase = mi*128;

  const int l  = t & 63;
  const int w  = t >> 6;
  const int wr = w >> 1, wc = w & 1;
  const uint32_t sh_base = (uint32_t)(uintptr_t)&sh.stage[0];
  const uint32_t laneA = ((uint32_t)(l>>4))*2048u + (uint32_t)wr*512u + (uint32_t)(l&15)*8u;
  const uint32_t laneB = ((uint32_t)(l>>4))*2048u + (uint32_t)wc*512u + (uint32_t)(l&15)*8u;
  const int off0 = ((rowg>>2)*8 + (colg>>4))*64 + (rowg&3)*16 + (colg&15);

  f32x4 acc[4][4];
  #pragma unroll
  for (int i=0;i<4;i++){
    #pragma unroll
    for (int j=0;j<4;j++){ f32x4 z = {0.f,0.f,0.f,0.f}; acc[i][j] = z; }
  }

  float sqA[8] = {0,0,0,0,0,0,0,0};
  float sqB[8] = {0,0,0,0,0,0,0,0};
  f4 ra[4], rb[4];

  auto load_tile = [&](int kt){
    const int c0 = kt*32 + rowg;
    const float* SA = Sb + (size_t)c0*HW;
    const float* RB = Rb + (size_t)c0*HW + mbase + colg;
    if (contig){
      const float* pA = SA + p0 + colg;
      ra[0] = *(const f4*)(pA);
      ra[1] = *(const f4*)(pA + 4);
      ra[2] = *(const f4*)(pA + 16*HW);
      ra[3] = *(const f4*)(pA + 16*HW + 4);
    } else {
      float* raf = (float*)ra;
      #pragma unroll
      for (int i=0;i<8;i++){
        const int pc = p_lds[colg + i];
        raf[i]   = SA[pc];
        raf[8+i] = SA[16*HW + pc];
      }
    }
    rb[0] = *(const f4*)(RB);
    rb[1] = *(const f4*)(RB + 4);
    rb[2] = *(const f4*)(RB + 16*HW);
    rb[3] = *(const f4*)(RB + 16*HW + 4);
  };

  auto cvt_store = [&](int buf){
    const float* raf = (const float*)ra;
    const float* rbf = (const float*)rb;
    us8 pk;
    #pragma unroll
    for (int i=0;i<8;i++){
      __hip_bfloat16 h = __float2bfloat16(raf[i]);
      pk[i] = __builtin_bit_cast(unsigned short, h);
      const float g = __bfloat162float(h);
      sqA[i] = fmaf(g, g, sqA[i]);
    }
    *(us8*)&sh.stage[buf*4096 + off0] = pk;
    #pragma unroll
    for (int i=0;i<8;i++){
      __hip_bfloat16 h = __float2bfloat16(raf[8+i]);
      pk[i] = __builtin_bit_cast(unsigned short, h);
      const float g = __bfloat162float(h);
      sqA[i] = fmaf(g, g, sqA[i]);
    }
    *(us8*)&sh.stage[buf*4096 + off0 + 2048] = pk;
    #pragma unroll
    for (int i=0;i<8;i++){
      __hip_bfloat16 h = __float2bfloat16(rbf[i]);
      pk[i] = __builtin_bit_cast(unsigned short, h);
      const float g = __bfloat162float(h);
      sqB[i] = fmaf(g, g, sqB[i]);
    }
    *(us8*)&sh.stage[8192 + buf*4096 + off0] = pk;
    #pragma unroll
    for (int i=0;i<8;i++){
      __hip_bfloat16 h = __float2bfloat16(rbf[8+i]);
      pk[i] = __builtin_bit_cast(unsigned short, h);
      const float g = __bfloat162float(h);
      sqB[i] = fmaf(g, g, sqB[i]);
    }
    *(us8*)&sh.stage[8192 + buf*4096 + off0 + 2048] = pk;
  };

  auto compute = [&](int buf){
    const uint32_t aaddr = sh_base + (uint32_t)buf*8192u + laneA;
    const uint32_t baddr = sh_base + 16384u + (uint32_t)buf*8192u + laneB;
    FragU A0,A1,A2,A3,B0,B1,B2,B3;
    A0.h[0]=tr_read<0>(aaddr);    A0.h[1]=tr_read<1024>(aaddr);
    A1.h[0]=tr_read<128>(aaddr);  A1.h[1]=tr_read<1152>(aaddr);
    A2.h[0]=tr_read<256>(aaddr);  A2.h[1]=tr_read<1280>(aaddr);
    A3.h[0]=tr_read<384>(aaddr);  A3.h[1]=tr_read<1408>(aaddr);
    B0.h[0]=tr_read<0>(baddr);    B0.h[1]=tr_read<1024>(baddr);
    B1.h[0]=tr_read<128>(baddr);  B1.h[1]=tr_read<1152>(baddr);
    B2.h[0]=tr_read<256>(baddr);  B2.h[1]=tr_read<1280>(baddr);
    B3.h[0]=tr_read<384>(baddr);  B3.h[1]=tr_read<1408>(baddr);
    asm volatile("s_waitcnt lgkmcnt(0)" ::: "memory");
    __builtin_amdgcn_sched_barrier(0);
    acc[0][0]=MFMA(A0.v,B0.v,acc[0][0],0,0,0);
    acc[0][1]=MFMA(A0.v,B1.v,acc[0][1],0,0,0);
    acc[0][2]=MFMA(A0.v,B2.v,acc[0][2],0,0,0);
    acc[0][3]=MFMA(A0.v,B3.v,acc[0][3],0,0,0);
    acc[1][0]=MFMA(A1.v,B0.v,acc[1][0],0,0,0);
    acc[1][1]=MFMA(A1.v,B1.v,acc[1][1],0,0,0);
    acc[1][2]=MFMA(A1.v,B2.v,acc[1][2],0,0,0);
    acc[1][3]=MFMA(A1.v,B3.v,acc[1][3],0,0,0);
    acc[2][0]=MFMA(A2.v,B0.v,acc[2][0],0,0,0);
    acc[2][1]=MFMA(A2.v,B1.v,acc[2][1],0,0,0);
    acc[2][2]=MFMA(A2.v,B2.v,acc[2][2],0,0,0);
    acc[2][3]=MFMA(A2.v,B3.v,acc[2][3],0,0,0);
    acc[3][0]=MFMA(A3.v,B0.v,acc[3][0],0,0,0);
    acc[3][1]=MFMA(A3.v,B1.v,acc[3][1],0,0,0);
    acc[3][2]=MFMA(A3.v,B2.v,acc[3][2],0,0,0);
    acc[3][3]=MFMA(A3.v,B3.v,acc[3][3],0,0,0);
  };

  load_tile(0);
  cvt_store(0);
  __syncthreads();
  int buf = 0;
  for (int kt = 0; kt < 32; ++kt){
    if (kt < 31) load_tile(kt+1);
    compute(buf);
    if (kt < 31) cvt_store(buf^1);
    __syncthreads();
    buf ^= 1;
  }

  #pragma unroll
  for (int i=0;i<8;i++) sh.nrm.nA[rowg][colg+i] = sqA[i];
  #pragma unroll
  for (int i=0;i<8;i++) sh.nrm.nB[rowg][colg+i] = sqB[i];
  __syncthreads();
  if (t < 128){
    float s = 0.f;
    #pragma unroll
    for (int r=0;r<16;r++) s += sh.nrm.nA[r][t];
    nA2[t] = s;
  } else {
    const int c2 = t - 128;
    float s = 0.f;
    #pragma unroll
    for (int r=0;r<16;r++) s += sh.nrm.nB[r][c2];
    nB2[c2] = s;
  }
  __syncthreads();

  float rncol[4];
  #pragma unroll
  for (int nf=0;nf<4;nf++) rncol[nf] = sqrtf(nB2[wc*64 + nf*16 + (l&15)]);

  #pragma unroll
  for (int mf=0; mf<4; ++mf){
    #pragma unroll
    for (int r=0; r<4; ++r){
      const int row_l = wr*64 + mf*16 + (l>>4)*4 + r;
      const int n_g   = ni*128 + row_l;
      const float an  = sqrtf(nA2[row_l]);
      const float v0 = acc[mf][0][r] / fmaxf(an*rncol[0], 1e-8f);
      const float v1 = acc[mf][1][r] / fmaxf(an*rncol[1], 1e-8f);
      const float v2 = acc[mf][2][r] / fmaxf(an*rncol[2], 1e-8f);
      const float v3 = acc[mf][3][r] / fmaxf(an*rncol[3], 1e-8f);

      const int* pp = posidx + (size_t)(b*NA + n_g)*3;
      const int q  = pp[2]*FWID + pp[1];
      const int ql = q - (mbase + wc*64);
      if (ql >= 0 && ql < 64 && (ql & 15) == (l & 15)){
        const int sel = ql >> 4;
        const float pv = sel==0 ? v0 : sel==1 ? v1 : sel==2 ? v2 : v3;
        wpos[b*NA + n_g] = pv;
      }

      float x=1e30f, y=1e30f, z=1e30f;
      ins3(x,y,z,v0); ins3(x,y,z,v1); ins3(x,y,z,v2); ins3(x,y,z,v3);
      #pragma unroll
      for (int m=1; m<16; m<<=1){
        const float ox = __shfl_xor(x, m);
        const float oy = __shfl_xor(y, m);
        const float oz = __shfl_xor(z, m);
        ins3(x,y,z,ox); ins3(x,y,z,oy); ins3(x,y,z,oz);
      }
      if ((l & 15) == 0){
        float* dst = wtop + ((size_t)(b*NA + n_g)*NCHUNK + (mi*2 + wc))*3;
        dst[0]=x; dst[1]=y; dst[2]=z;
      }
    }
  }
}

// ---------------------------------------------------------------------------
__global__ __launch_bounds__(256)
void merge_top3(const float* __restrict__ wtop, const float* __restrict__ wpos,
                float* __restrict__ partial){
  __shared__ float red[256];
  const int id = blockIdx.x*256 + threadIdx.x;
  const float* src = wtop + (size_t)id*(NCHUNK*3);
  float x=1e30f, y=1e30f, z=1e30f;
  #pragma unroll
  for (int i=0;i<NCHUNK*3;i++) ins3(x,y,z, src[i]);
  const float loss = fmaxf((x+y+z) - wpos[id] + MARGIN, 0.0f);
  red[threadIdx.x] = loss;
  __syncthreads();
  for (int s=128; s>0; s>>=1){
    if (threadIdx.x < s) red[threadIdx.x] += red[threadIdx.x+s];
    __syncthreads();
  }
  if (threadIdx.x == 0) partial[blockIdx.x] = red[0];
}

__global__ void final_sum(const float* __restrict__ partial, float* __restrict__ out){
  float v = partial[threadIdx.x];
  #pragma unroll
  for (int off=32; off>0; off>>=1) v += __shfl_down(v, off);
  if (threadIdx.x == 0) out[0] = v / (1e-6f + (float)NTOT);
}

// ---------------------------------------------------------------------------
extern "C" void kernel_launch(void* const* d_in, const int* in_sizes, int n_in,
                              void* d_out, int out_size, void* d_ws, size_t ws_size,
                              hipStream_t stream){
  const float* sketch = (const float*)d_in[0];
  const float* refk   = (const float*)d_in[1];
  const int*   anchor = (const int*)d_in[2];
  const int*   posidx = (const int*)d_in[3];
  float* out = (float*)d_out;

  float* wtop    = (float*)d_ws;                       // NTOT*NCHUNK*3 floats
  float* wpos    = wtop + (size_t)NTOT*NCHUNK*3;       // NTOT floats
  float* partial = wpos + NTOT;                        // 64 floats (+pad)
  unsigned short* tS = (unsigned short*)(partial + 256);
  unsigned short* tR = tS + (size_t)BATCH*HW*CDIM;
  float* pnorm = (float*)(tR + (size_t)BATCH*HW*CDIM); // 32*8*1024 floats
  float* snorm = pnorm + (size_t)32*8*1024;            // 32*1024 floats
  const size_t need = (size_t)((char*)(snorm + 32*1024) - (char*)d_ws);

  if (ws_size >= need){
    convert_transpose<<<dim3(4096), dim3(256), 0, stream>>>(sketch, refk, tS, tR, pnorm);
    norm_reduce<<<dim3(32), dim3(256), 0, stream>>>(pnorm, snorm);
    fused_gemm_top3_v3<<<dim3(1024), dim3(256), 0, stream>>>(tS, tR, snorm, anchor, posidx, wtop, wpos);
  } else {
    fused_gemm_top3_v1<<<dim3(1024), dim3(256), 0, stream>>>(sketch, refk, anchor, posidx, wtop, wpos);
  }
  merge_top3<<<dim3(64), dim3(256), 0, stream>>>(wtop, wpos, partial);
  final_sum<<<dim3(1), dim3(64), 0, stream>>>(partial, out);
}

// Round 7
// 124.054 us; speedup vs baseline: 1.0743x; 1.0743x over previous
//
#include <hip/hip_runtime.h>
#include <hip/hip_bf16.h>
#include <stdint.h>

// ---------------- problem constants ----------------
#define BATCH 16
#define CDIM  1024
#define FWID  32
#define HW    1024
#define NA    1024
#define NTOT  (BATCH*NA)    // 16384
#define NCHUNK 16           // 4 mi-tiles * 4 wc waves = 16 chunks of 64 cols
#define MARGIN 0.6f

typedef __bf16 bf16x8 __attribute__((ext_vector_type(8)));
typedef float  f32x4  __attribute__((ext_vector_type(4)));
typedef unsigned short us4 __attribute__((ext_vector_type(4)));
typedef unsigned short us8 __attribute__((ext_vector_type(8)));
typedef float  f4     __attribute__((ext_vector_type(4)));

template<int OFF>
__device__ __forceinline__ us4 tr_read(uint32_t addr){
  us4 r;
  asm volatile("ds_read_b64_tr_b16 %0, %1 offset:%2" : "=v"(r) : "v"(addr), "n"(OFF));
  return r;
}

__device__ __forceinline__ void gload16(const unsigned short* g, unsigned short* l){
  __builtin_amdgcn_global_load_lds((const __attribute__((address_space(1))) void*)g,
                                   (__attribute__((address_space(3))) void*)l, 16, 0, 0);
}

union FragU  { us4 h[2]; bf16x8 v; };
union FragU8 { us8 u;    bf16x8 v; };

__device__ __forceinline__ void ins3(float& a, float& b, float& c, float v){
  if (v < c){
    c = v;
    if (c < b){ float t=b; b=c; c=t;
      if (b < a){ t=a; a=b; b=t; }
    }
  }
}

#define MFMA __builtin_amdgcn_mfma_f32_16x16x32_bf16

// ---------------------------------------------------------------------------
// Pass 1: fp32 [c][hw] -> bf16 TRANSPOSED [hw][c] + per-hw norm partials.
// grid: e(2) x b(16) x hwT(16: 64hw) x cT(8: 128c) = 4096 blocks, 256 threads.
// Thread: cj = t&15 (8 c's), hwg = t>>4 (4 hw's). Reads 8x f4 (lanes sharing a
// c-row cover 64B); register 8x4 micro-transpose; writes 4x us8 (16 lanes ->
// 256B contiguous per hw row). No LDS, no cross-thread transpose.
// ---------------------------------------------------------------------------
__global__ __launch_bounds__(256)
void convert_transpose(const float* __restrict__ S, const float* __restrict__ R,
                       unsigned short* __restrict__ tS, unsigned short* __restrict__ tR,
                       float* __restrict__ pnorm){
  const int blk = blockIdx.x;
  const int e   = blk >> 11;
  const int b   = (blk >> 7) & 15;
  const int hwT = (blk >> 3) & 15;
  const int cT  = blk & 7;
  const float* src = (e ? R : S) + (size_t)b*CDIM*HW;
  unsigned short* dst = (e ? tR : tS) + (size_t)b*HW*CDIM;

  const int t   = threadIdx.x;
  const int cj  = t & 15;
  const int hwg = t >> 4;
  const int hw0 = hwT*64 + hwg*4;
  const int c0  = cT*128 + cj*8;

  f4 col[8];
  #pragma unroll
  for (int i = 0; i < 8; ++i)
    col[i] = *(const f4*)&src[(size_t)(c0 + i)*HW + hw0];

  float sq0=0.f, sq1=0.f, sq2=0.f, sq3=0.f;
  #pragma unroll
  for (int j = 0; j < 4; ++j){
    us8 pk;
    float sq = 0.f;
    #pragma unroll
    for (int i = 0; i < 8; ++i){
      __hip_bfloat16 h = __float2bfloat16(col[i][j]);
      pk[i] = __builtin_bit_cast(unsigned short, h);
      const float g = __bfloat162float(h);
      sq = fmaf(g, g, sq);
    }
    *(us8*)&dst[(size_t)(hw0 + j)*CDIM + c0] = pk;
    if (j==0) sq0=sq; else if (j==1) sq1=sq; else if (j==2) sq2=sq; else sq3=sq;
  }
  // reduce over cj within each 16-lane group (same hwg)
  #pragma unroll
  for (int m = 1; m < 16; m <<= 1){
    sq0 += __shfl_xor(sq0, m);
    sq1 += __shfl_xor(sq1, m);
    sq2 += __shfl_xor(sq2, m);
    sq3 += __shfl_xor(sq3, m);
  }
  if (cj == 0){
    f4 o = {sq0, sq1, sq2, sq3};
    *(f4*)&pnorm[((size_t)(e*16 + b)*8 + cT)*HW + hw0] = o;
  }
}

// grid: 32 blocks [e*16+b], 256 threads; snorm = sqrt(sum of 8 partials)
__global__ __launch_bounds__(256)
void norm_reduce(const float* __restrict__ pnorm, float* __restrict__ snorm){
  const int eb = blockIdx.x;
  const int t  = threadIdx.x;
  #pragma unroll
  for (int r = 0; r < 4; ++r){
    const int hw = r*256 + t;
    float a = 0.f;
    #pragma unroll
    for (int ct = 0; ct < 8; ++ct)
      a += pnorm[((size_t)eb*8 + ct)*HW + hw];
    snorm[(size_t)eb*HW + hw] = sqrtf(a);
  }
}

// ---------------------------------------------------------------------------
// Pass 2 (v4): 256x256 tile, BK=32, 8 waves (2M x 4N), 3 LDS buffers,
// depth-2 prefetch, ONE barrier + counted vmcnt(4) per K-tile (non-draining),
// conflict-free XOR swizzle pc = kc ^ ((row>>1)&3) (pre-swizzled global src).
// Per-wave: 128x64 C = acc[8][4]; 12 ds_read_b128 + 32 MFMA per tile.
// ---------------------------------------------------------------------------
__global__ __launch_bounds__(512, 2)
void fused_gemm_top3_v4(const unsigned short* __restrict__ tS,
                        const unsigned short* __restrict__ tR,
                        const float* __restrict__ snorm,
                        const int*   __restrict__ anchor,
                        const int*   __restrict__ posidx,
                        float* __restrict__ wtop,   // [NTOT][NCHUNK][3]
                        float* __restrict__ wpos)   // [NTOT]
{
  // A: us [0, 24576) = 3 bufs x 8192 us (16KB: 256 rows x 32 k);
  // B: us [24576, 49152). Total 96KB + 6KB aux.
  __shared__ unsigned short stage[49152];
  __shared__ int   p_lds[256], q_lds[256];
  __shared__ float nAs[256], nBs[256];

  const int t = threadIdx.x;
  const uint32_t bid = blockIdx.x;
  const uint32_t L = (bid & 7u)*32u + (bid >> 3);   // XCD swizzle (256%8==0 bijective)
  const int b  = L >> 4;
  const int ni = (L >> 2) & 3;
  const int mi = L & 3;

  const unsigned short* SbT = tS + (size_t)b*HW*CDIM;
  const unsigned short* RbT = tR + (size_t)b*HW*CDIM;

  if (t < 256){
    const int n_g = ni*256 + t;
    const int* ap = anchor + (size_t)(b*NA + n_g)*3;
    const int* pp = posidx + (size_t)(b*NA + n_g)*3;
    const int pv = ap[2]*FWID + ap[1];
    p_lds[t] = pv;
    q_lds[t] = pp[2]*FWID + pp[1];
    nAs[t] = snorm[(size_t)b*HW + pv];
  } else {
    nBs[t-256] = snorm[(size_t)(BATCH + b)*HW + mi*256 + (t-256)];
  }
  __syncthreads();

  const int l  = t & 63;
  const int w  = t >> 6;            // 0..7
  const int wr = w >> 2, wc = w & 3;

  // ---- staging: wave w covers rows w*32..w*32+31 of the 256-row tile.
  // inst covers 1KB: row = w*32 + inst*16 + (l>>2), stored chunk pc = l&3.
  // Pre-swizzled global k-chunk: gkc = pc ^ ((row>>1)&3) = (l&3) ^ ((l>>3)&3).
  const int gkc = (l&3) ^ ((l>>3)&3);
  const int r0  = w*32 + (l>>2);
  const int r1  = r0 + 16;
  const unsigned short* gA0 = SbT + (size_t)p_lds[r0]*CDIM + gkc*8;
  const unsigned short* gA1 = SbT + (size_t)p_lds[r1]*CDIM + gkc*8;
  const unsigned short* gB0 = RbT + (size_t)(mi*256 + r0)*CDIM + gkc*8;
  const unsigned short* gB1 = RbT + (size_t)(mi*256 + r1)*CDIM + gkc*8;
  unsigned short* lA = &stage[w*1024];
  unsigned short* lB = &stage[24576 + w*1024];

  // ---- frag read base (us units): row*32 + (kc ^ ((row>>1)&3))*8,
  // row = base16 + (l&15), kc = l>>4  ->  swz = (l>>4) ^ ((l>>1)&3).
  const int fbase = (l&15)*32 + (((l>>4) ^ ((l>>1)&3))*8);
  const int abase = wr*4096 + fbase;             // wr*128 rows * 32 us
  const int bbase = 24576 + wc*2048 + fbase;     // wc*64 rows * 32 us

  f32x4 acc[8][4];
  #pragma unroll
  for (int i=0;i<8;i++){
    #pragma unroll
    for (int j=0;j<4;j++){ f32x4 z = {0.f,0.f,0.f,0.f}; acc[i][j] = z; }
  }

  auto stage_fn = [&](int bo, int kt){
    const int ko = kt*32;
    gload16(gA0 + ko, lA + bo);
    gload16(gA1 + ko, lA + bo + 512);
    gload16(gB0 + ko, lB + bo);
    gload16(gB1 + ko, lB + bo + 512);
  };

  auto compute = [&](int bo){
    FragU8 Bf[4], Af[8];
    #pragma unroll
    for (int fb=0; fb<4; ++fb) Bf[fb].u = *(const us8*)&stage[bbase + bo + fb*512];
    #pragma unroll
    for (int fa=0; fa<8; ++fa) Af[fa].u = *(const us8*)&stage[abase + bo + fa*512];
    #pragma unroll
    for (int fa=0; fa<8; ++fa){
      #pragma unroll
      for (int fb=0; fb<4; ++fb)
        acc[fa][fb] = MFMA(Af[fa].v, Bf[fb].v, acc[fa][fb], 0,0,0);
    }
  };

  // ---- main K loop: 32 tiles, 3 bufs, depth-2 prefetch, 1 barrier/tile ----
  stage_fn(0, 0);
  stage_fn(8192, 1);
  int oc = 0, on = 8192, on2 = 16384;
  for (int kt = 0; kt < 32; ++kt){
    if (kt < 31) asm volatile("s_waitcnt vmcnt(4)" ::: "memory");   // tile kt landed; kt+1 in flight
    else         asm volatile("s_waitcnt vmcnt(0)" ::: "memory");
    asm volatile("s_waitcnt lgkmcnt(0)" ::: "memory");              // own frag reads drained (WAR fence)
    __builtin_amdgcn_s_barrier();
    if (kt < 30) stage_fn(on2, kt+2);                               // overwrite buf freed at kt-1
    compute(oc);
    const int tmp = oc; oc = on; on = on2; on2 = tmp;
  }

  // ---- epilogue: normalize, positive capture, per-row top3-min ----
  float rncol[4];
  #pragma unroll
  for (int fb=0; fb<4; ++fb) rncol[fb] = nBs[wc*64 + fb*16 + (l&15)];

  #pragma unroll
  for (int fa=0; fa<8; ++fa){
    #pragma unroll
    for (int r=0; r<4; ++r){
      const int row_l = wr*128 + fa*16 + (l>>4)*4 + r;   // D: col=lane&15, row=(lane>>4)*4+reg
      const int n_g   = ni*256 + row_l;
      const float an  = nAs[row_l];
      const float v0 = acc[fa][0][r] / fmaxf(an*rncol[0], 1e-8f);
      const float v1 = acc[fa][1][r] / fmaxf(an*rncol[1], 1e-8f);
      const float v2 = acc[fa][2][r] / fmaxf(an*rncol[2], 1e-8f);
      const float v3 = acc[fa][3][r] / fmaxf(an*rncol[3], 1e-8f);

      const int q  = q_lds[row_l];
      const int ql = q - (mi*256 + wc*64);
      if (ql >= 0 && ql < 64 && (ql & 15) == (l & 15)){
        const int sel = ql >> 4;
        const float pv = sel==0 ? v0 : sel==1 ? v1 : sel==2 ? v2 : v3;
        wpos[b*NA + n_g] = pv;
      }

      float x=1e30f, y=1e30f, z=1e30f;
      ins3(x,y,z,v0); ins3(x,y,z,v1); ins3(x,y,z,v2); ins3(x,y,z,v3);
      #pragma unroll
      for (int m=1; m<16; m<<=1){
        const float ox = __shfl_xor(x, m);
        const float oy = __shfl_xor(y, m);
        const float oz = __shfl_xor(z, m);
        ins3(x,y,z,ox); ins3(x,y,z,oy); ins3(x,y,z,oz);
      }
      if ((l & 15) == 0){
        float* dst = wtop + ((size_t)(b*NA + n_g)*NCHUNK + (mi*4 + wc))*3;
        dst[0]=x; dst[1]=y; dst[2]=z;
      }
    }
  }
}

// ---------------------------------------------------------------------------
// v1 (verified) fused kernel — fallback when workspace is too small.
// ---------------------------------------------------------------------------
__global__ __launch_bounds__(256)
void fused_gemm_top3_v1(const float* __restrict__ sketch,
                        const float* __restrict__ refk,
                        const int*   __restrict__ anchor,
                        const int*   __restrict__ posidx,
                        float* __restrict__ wtop,
                        float* __restrict__ wpos)
{
  __shared__ union {
    unsigned short stage[16384];
    struct { float nA[16][128]; float nB[16][128]; } nrm;
  } sh;
  __shared__ int   p_lds[128];
  __shared__ float nA2[128], nB2[128];

  const int t = threadIdx.x;
  const uint32_t bid = blockIdx.x;
  const uint32_t L = (bid & 7u)*128u + (bid >> 3);
  const int b  = L >> 6;
  const int ni = (L >> 3) & 7;
  const int mi = L & 7;

  const float* Sb = sketch + (size_t)b*CDIM*HW;
  const float* Rb = refk   + (size_t)b*CDIM*HW;

  if (t < 128){
    const int n_g = ni*128 + t;
    const int* ap = anchor + (size_t)(b*NA + n_g)*3;
    p_lds[t] = ap[2]*FWID + ap[1];
  }
  __syncthreads();
  const int p0 = p_lds[0];
  int okf = 1;
  if (t < 128) okf = (p_lds[t] == p0 + t);
  const int contig = __syncthreads_and(okf);

  const int colg = (t & 15)*8;
  const int rowg = t >> 4;
  const int mbase = mi*128;

  const int l  = t & 63;
  const int w  = t >> 6;
  const int wr = w >> 1, wc = w & 1;
  const uint32_t sh_base = (uint32_t)(uintptr_t)&sh.stage[0];
  const uint32_t laneA = ((uint32_t)(l>>4))*2048u + (uint32_t)wr*512u + (uint32_t)(l&15)*8u;
  const uint32_t laneB = ((uint32_t)(l>>4))*2048u + (uint32_t)wc*512u + (uint32_t)(l&15)*8u;
  const int off0 = ((rowg>>2)*8 + (colg>>4))*64 + (rowg&3)*16 + (colg&15);

  f32x4 acc[4][4];
  #pragma unroll
  for (int i=0;i<4;i++){
    #pragma unroll
    for (int j=0;j<4;j++){ f32x4 z = {0.f,0.f,0.f,0.f}; acc[i][j] = z; }
  }

  float sqA[8] = {0,0,0,0,0,0,0,0};
  float sqB[8] = {0,0,0,0,0,0,0,0};
  f4 ra[4], rb[4];

  auto load_tile = [&](int kt){
    const int c0 = kt*32 + rowg;
    const float* SA = Sb + (size_t)c0*HW;
    const float* RB = Rb + (size_t)c0*HW + mbase + colg;
    if (contig){
      const float* pA = SA + p0 + colg;
      ra[0] = *(const f4*)(pA);
      ra[1] = *(const f4*)(pA + 4);
      ra[2] = *(const f4*)(pA + 16*HW);
      ra[3] = *(const f4*)(pA + 16*HW + 4);
    } else {
      float* raf = (float*)ra;
      #pragma unroll
      for (int i=0;i<8;i++){
        const int pc = p_lds[colg + i];
        raf[i]   = SA[pc];
        raf[8+i] = SA[16*HW + pc];
      }
    }
    rb[0] = *(const f4*)(RB);
    rb[1] = *(const f4*)(RB + 4);
    rb[2] = *(const f4*)(RB + 16*HW);
    rb[3] = *(const f4*)(RB + 16*HW + 4);
  };

  auto cvt_store = [&](int buf){
    const float* raf = (const float*)ra;
    const float* rbf = (const float*)rb;
    us8 pk;
    #pragma unroll
    for (int i=0;i<8;i++){
      __hip_bfloat16 h = __float2bfloat16(raf[i]);
      pk[i] = __builtin_bit_cast(unsigned short, h);
      const float g = __bfloat162float(h);
      sqA[i] = fmaf(g, g, sqA[i]);
    }
    *(us8*)&sh.stage[buf*4096 + off0] = pk;
    #pragma unroll
    for (int i=0;i<8;i++){
      __hip_bfloat16 h = __float2bfloat16(raf[8+i]);
      pk[i] = __builtin_bit_cast(unsigned short, h);
      const float g = __bfloat162float(h);
      sqA[i] = fmaf(g, g, sqA[i]);
    }
    *(us8*)&sh.stage[buf*4096 + off0 + 2048] = pk;
    #pragma unroll
    for (int i=0;i<8;i++){
      __hip_bfloat16 h = __float2bfloat16(rbf[i]);
      pk[i] = __builtin_bit_cast(unsigned short, h);
      const float g = __bfloat162float(h);
      sqB[i] = fmaf(g, g, sqB[i]);
    }
    *(us8*)&sh.stage[8192 + buf*4096 + off0] = pk;
    #pragma unroll
    for (int i=0;i<8;i++){
      __hip_bfloat16 h = __float2bfloat16(rbf[8+i]);
      pk[i] = __builtin_bit_cast(unsigned short, h);
      const float g = __bfloat162float(h);
      sqB[i] = fmaf(g, g, sqB[i]);
    }
    *(us8*)&sh.stage[8192 + buf*4096 + off0 + 2048] = pk;
  };

  auto compute = [&](int buf){
    const uint32_t aaddr = sh_base + (uint32_t)buf*8192u + laneA;
    const uint32_t baddr = sh_base + 16384u + (uint32_t)buf*8192u + laneB;
    FragU A0,A1,A2,A3,B0,B1,B2,B3;
    A0.h[0]=tr_read<0>(aaddr);    A0.h[1]=tr_read<1024>(aaddr);
    A1.h[0]=tr_read<128>(aaddr);  A1.h[1]=tr_read<1152>(aaddr);
    A2.h[0]=tr_read<256>(aaddr);  A2.h[1]=tr_read<1280>(aaddr);
    A3.h[0]=tr_read<384>(aaddr);  A3.h[1]=tr_read<1408>(aaddr);
    B0.h[0]=tr_read<0>(baddr);    B0.h[1]=tr_read<1024>(baddr);
    B1.h[0]=tr_read<128>(baddr);  B1.h[1]=tr_read<1152>(baddr);
    B2.h[0]=tr_read<256>(baddr);  B2.h[1]=tr_read<1280>(baddr);
    B3.h[0]=tr_read<384>(baddr);  B3.h[1]=tr_read<1408>(baddr);
    asm volatile("s_waitcnt lgkmcnt(0)" ::: "memory");
    __builtin_amdgcn_sched_barrier(0);
    acc[0][0]=MFMA(A0.v,B0.v,acc[0][0],0,0,0);
    acc[0][1]=MFMA(A0.v,B1.v,acc[0][1],0,0,0);
    acc[0][2]=MFMA(A0.v,B2.v,acc[0][2],0,0,0);
    acc[0][3]=MFMA(A0.v,B3.v,acc[0][3],0,0,0);
    acc[1][0]=MFMA(A1.v,B0.v,acc[1][0],0,0,0);
    acc[1][1]=MFMA(A1.v,B1.v,acc[1][1],0,0,0);
    acc[1][2]=MFMA(A1.v,B2.v,acc[1][2],0,0,0);
    acc[1][3]=MFMA(A1.v,B3.v,acc[1][3],0,0,0);
    acc[2][0]=MFMA(A2.v,B0.v,acc[2][0],0,0,0);
    acc[2][1]=MFMA(A2.v,B1.v,acc[2][1],0,0,0);
    acc[2][2]=MFMA(A2.v,B2.v,acc[2][2],0,0,0);
    acc[2][3]=MFMA(A2.v,B3.v,acc[2][3],0,0,0);
    acc[3][0]=MFMA(A3.v,B0.v,acc[3][0],0,0,0);
    acc[3][1]=MFMA(A3.v,B1.v,acc[3][1],0,0,0);
    acc[3][2]=MFMA(A3.v,B2.v,acc[3][2],0,0,0);
    acc[3][3]=MFMA(A3.v,B3.v,acc[3][3],0,0,0);
  };

  load_tile(0);
  cvt_store(0);
  __syncthreads();
  int buf = 0;
  for (int kt = 0; kt < 32; ++kt){
    if (kt < 31) load_tile(kt+1);
    compute(buf);
    if (kt < 31) cvt_store(buf^1);
    __syncthreads();
    buf ^= 1;
  }

  #pragma unroll
  for (int i=0;i<8;i++) sh.nrm.nA[rowg][colg+i] = sqA[i];
  #pragma unroll
  for (int i=0;i<8;i++) sh.nrm.nB[rowg][colg+i] = sqB[i];
  __syncthreads();
  if (t < 128){
    float s = 0.f;
    #pragma unroll
    for (int r=0;r<16;r++) s += sh.nrm.nA[r][t];
    nA2[t] = s;
  } else {
    const int c2 = t - 128;
    float s = 0.f;
    #pragma unroll
    for (int r=0;r<16;r++) s += sh.nrm.nB[r][c2];
    nB2[c2] = s;
  }
  __syncthreads();

  float rncol[4];
  #pragma unroll
  for (int nf=0;nf<4;nf++) rncol[nf] = sqrtf(nB2[wc*64 + nf*16 + (l&15)]);

  #pragma unroll
  for (int mf=0; mf<4; ++mf){
    #pragma unroll
    for (int r=0; r<4; ++r){
      const int row_l = wr*64 + mf*16 + (l>>4)*4 + r;
      const int n_g   = ni*128 + row_l;
      const float an  = sqrtf(nA2[row_l]);
      const float v0 = acc[mf][0][r] / fmaxf(an*rncol[0], 1e-8f);
      const float v1 = acc[mf][1][r] / fmaxf(an*rncol[1], 1e-8f);
      const float v2 = acc[mf][2][r] / fmaxf(an*rncol[2], 1e-8f);
      const float v3 = acc[mf][3][r] / fmaxf(an*rncol[3], 1e-8f);

      const int* pp = posidx + (size_t)(b*NA + n_g)*3;
      const int q  = pp[2]*FWID + pp[1];
      const int ql = q - (mbase + wc*64);
      if (ql >= 0 && ql < 64 && (ql & 15) == (l & 15)){
        const int sel = ql >> 4;
        const float pv = sel==0 ? v0 : sel==1 ? v1 : sel==2 ? v2 : v3;
        wpos[b*NA + n_g] = pv;
      }

      float x=1e30f, y=1e30f, z=1e30f;
      ins3(x,y,z,v0); ins3(x,y,z,v1); ins3(x,y,z,v2); ins3(x,y,z,v3);
      #pragma unroll
      for (int m=1; m<16; m<<=1){
        const float ox = __shfl_xor(x, m);
        const float oy = __shfl_xor(y, m);
        const float oz = __shfl_xor(z, m);
        ins3(x,y,z,ox); ins3(x,y,z,oy); ins3(x,y,z,oz);
      }
      if ((l & 15) == 0){
        float* dst = wtop + ((size_t)(b*NA + n_g)*NCHUNK + (mi*2 + wc))*3;
        dst[0]=x; dst[1]=y; dst[2]=z;
      }
    }
  }
}

// ---------------------------------------------------------------------------
__global__ __launch_bounds__(256)
void merge_top3(const float* __restrict__ wtop, const float* __restrict__ wpos,
                float* __restrict__ partial){
  __shared__ float red[256];
  const int id = blockIdx.x*256 + threadIdx.x;
  const float* src = wtop + (size_t)id*(NCHUNK*3);
  float x=1e30f, y=1e30f, z=1e30f;
  #pragma unroll
  for (int i=0;i<NCHUNK*3;i++) ins3(x,y,z, src[i]);
  const float loss = fmaxf((x+y+z) - wpos[id] + MARGIN, 0.0f);
  red[threadIdx.x] = loss;
  __syncthreads();
  for (int s=128; s>0; s>>=1){
    if (threadIdx.x < s) red[threadIdx.x] += red[threadIdx.x+s];
    __syncthreads();
  }
  if (threadIdx.x == 0) partial[blockIdx.x] = red[0];
}

__global__ void final_sum(const float* __restrict__ partial, float* __restrict__ out){
  float v = partial[threadIdx.x];
  #pragma unroll
  for (int off=32; off>0; off>>=1) v += __shfl_down(v, off);
  if (threadIdx.x == 0) out[0] = v / (1e-6f + (float)NTOT);
}

// ---------------------------------------------------------------------------
extern "C" void kernel_launch(void* const* d_in, const int* in_sizes, int n_in,
                              void* d_out, int out_size, void* d_ws, size_t ws_size,
                              hipStream_t stream){
  const float* sketch = (const float*)d_in[0];
  const float* refk   = (const float*)d_in[1];
  const int*   anchor = (const int*)d_in[2];
  const int*   posidx = (const int*)d_in[3];
  float* out = (float*)d_out;

  float* wtop    = (float*)d_ws;                       // NTOT*NCHUNK*3 floats
  float* wpos    = wtop + (size_t)NTOT*NCHUNK*3;       // NTOT floats
  float* partial = wpos + NTOT;                        // 64 floats (+pad)
  unsigned short* tS = (unsigned short*)(partial + 256);
  unsigned short* tR = tS + (size_t)BATCH*HW*CDIM;
  float* pnorm = (float*)(tR + (size_t)BATCH*HW*CDIM); // 32*8*1024 floats
  float* snorm = pnorm + (size_t)32*8*1024;            // 32*1024 floats
  const size_t need = (size_t)((char*)(snorm + 32*1024) - (char*)d_ws);

  if (ws_size >= need){
    convert_transpose<<<dim3(4096), dim3(256), 0, stream>>>(sketch, refk, tS, tR, pnorm);
    norm_reduce<<<dim3(32), dim3(256), 0, stream>>>(pnorm, snorm);
    fused_gemm_top3_v4<<<dim3(256), dim3(512), 0, stream>>>(tS, tR, snorm, anchor, posidx, wtop, wpos);
  } else {
    fused_gemm_top3_v1<<<dim3(1024), dim3(256), 0, stream>>>(sketch, refk, anchor, posidx, wtop, wpos);
  }
  merge_top3<<<dim3(64), dim3(256), 0, stream>>>(wtop, wpos, partial);
  final_sum<<<dim3(1), dim3(64), 0, stream>>>(partial, out);
}